// Round 2
// baseline (27.804 us; speedup 1.0000x reference)
//
#include <hip/hip_runtime.h>
#include <hip/hip_bf16.h>

// Problem constants (fixed by the reference)
#define NG   1024
#define IMGW 256
#define IMGH 256
#define NC   64
#define CULL_T 15.0f   // cull when sigma > T; dropped mass <= 1024*2*0.07*e^-15 ~ 4e-5

__device__ __forceinline__ int opaque_v(int x) {
    // Defeat uniformity analysis: keep dependent loads on the VECTOR path
    // (global_load broadcast) instead of scalarizing to s_load (SGPR budget
    // can't hold a double-buffered 64-float feature row).
    int y; asm("v_mov_b32 %0, %1" : "=v"(y) : "v"(x)); return y;
}

// ---------------------------------------------------------------------------
// Kernel 1: per-gaussian parameter precompute + softplus(features) into ws.
// blocks 0..255: feats (65536 softplus). block 256: 1024 gaussians, 4/thread.
// ---------------------------------------------------------------------------
__global__ __launch_bounds__(256) void prep_kernel(
    const float* __restrict__ xyz,  const float* __restrict__ chol,
    const float* __restrict__ opac, const float* __restrict__ fdc,
    const float* __restrict__ gfrq, const float* __restrict__ gwts,
    float*  __restrict__ feats, float4* __restrict__ cull,
    float4* __restrict__ coef,  float4* __restrict__ gab,
    float2* __restrict__ wts)
{
    const int b = blockIdx.x, t = threadIdx.x;
    if (b < 256) {
        const int i = (b << 8) + t;
        const float x = fdc[i];
        feats[i] = x > 0.f ? x + log1pf(expf(-x)) : log1pf(expf(x));
        return;
    }
    for (int j = 0; j < 4; ++j) {
        const int n = (j << 8) + t;
        const float2 xy = ((const float2*)xyz)[n];
        const float xs = 128.f * (tanhf(xy.x) + 1.f);
        const float ys = 128.f * (tanhf(xy.y) + 1.f);

        const float l1 = chol[3*n]     + 0.5f;
        const float l2 = chol[3*n + 1];
        const float l3 = chol[3*n + 2] + 0.5f;
        const float s11 = l1*l1, s12 = l1*l2, s22 = l2*l2 + l3*l3;
        const float dt  = (l1*l3) * (l1*l3);
        const float ca = s22/dt, cb = -(s12/dt), cc = s11/dt;
        const float mid = 0.5f*(s11 + s22);
        const float lam = mid + sqrtf(fmaxf(mid*mid - dt, 1e-8f));
        const float radius = ceilf(3.f * sqrtf(lam));
        const float keep = (radius > 1.0f) ? 1.f : 0.f;   // RADIUS_CLIP = 1.0
        const float oK = opac[n] * keep;
        const float r2 = (oK != 0.f) ? (2.f * CULL_T * lam) : -1.f;

        cull[n] = make_float4(xs, ys, r2, oK);
        coef[n] = make_float4(ca, cb, cc, 0.f);
        const float4 gf = ((const float4*)gfrq)[n];
        gab[n]  = make_float4(expf(gf.x), expf(gf.y), expf(gf.z), expf(gf.w));
        const float2 gw = ((const float2*)gwts)[n];
        wts[n]  = make_float2(1.f/(1.f + expf(-gw.x)), 1.f/(1.f + expf(-gw.y)));
    }
}

// ---------------------------------------------------------------------------
// Kernel 2: one block per 32x8 pixel tile (256 blocks = 1/CU, 1 wave/SIMD).
// Deterministic ballot-compaction, then a register-level software-pipelined
// accumulation loop: while gaussian i's ~210-cycle compute runs, gaussian
// i+1's params (scalar path) and 64-float feature row (vector path, uniform
// address -> broadcast) are already in flight. VGPRs are free at 1 wave/SIMD.
// ---------------------------------------------------------------------------
__global__ __launch_bounds__(256, 1) void render_kernel(
    const float*  __restrict__ feats, const float4* __restrict__ cull,
    const float4* __restrict__ coef,  const float4* __restrict__ gab,
    const float2* __restrict__ wts,   float* __restrict__ out)
{
    __shared__ unsigned short s_ids[4][256];
    __shared__ int            s_cnt[4];
    __shared__ unsigned short s_list[NG];

    const int tid  = threadIdx.x;
    const int lane = tid & 63, w = tid >> 6;

    const int x0 = (blockIdx.x & 7) << 5;   // 8 tiles across (32 px wide)
    const int y0 = (blockIdx.x >> 3) << 3;  // 32 tiles down  (8 px tall)
    const float xlo = x0 + 0.5f, xhi = x0 + 31.5f;
    const float ylo = y0 + 0.5f, yhi = y0 + 7.5f;

    // phase A: each wave owns 256 gaussians, 4 ordered rounds of 64
    int cnt = 0;
    for (int r = 0; r < 4; ++r) {
        const int n = (w << 8) + (r << 6) + lane;
        const float4 cu = cull[n];
        const float nx = fminf(fmaxf(cu.x, xlo), xhi);
        const float ny = fminf(fmaxf(cu.y, ylo), yhi);
        const float ddx = cu.x - nx, ddy = cu.y - ny;
        const bool live = (ddx*ddx + ddy*ddy) <= cu.z;   // r2 = -1 kills dead ones
        const unsigned long long m = __ballot(live);
        if (live) {
            const int pos = cnt + __popcll(m & ((1ull << lane) - 1ull));
            s_ids[w][pos] = (unsigned short)n;
        }
        cnt += __popcll(m);
    }
    if (lane == 0) s_cnt[w] = cnt;
    __syncthreads();

    // merge per-wave lists in wave order -> globally ascending ids (determinism)
    const int c0 = s_cnt[0], c1 = s_cnt[1], c2 = s_cnt[2], c3 = s_cnt[3];
    const int offw = (w > 0 ? c0 : 0) + (w > 1 ? c1 : 0) + (w > 2 ? c2 : 0);
    const int myc = s_cnt[w];
    for (int i = lane; i < myc; i += 64) s_list[offw + i] = s_ids[w][i];
    __syncthreads();
    const int total = __builtin_amdgcn_readfirstlane(c0 + c1 + c2 + c3);

    // phase B: per-pixel accumulation, 2-stage pipelined
    const int tx = tid & 31, ty = tid >> 5;
    const float px = x0 + tx + 0.5f;
    const float py = y0 + ty + 0.5f;

    float acc[NC];
    #pragma unroll
    for (int c = 0; c < NC; ++c) acc[c] = 0.f;

    // named double buffers (static indexing only — rule #20)
    float4 A_cu, A_cf, A_gb, B_cu, B_cf, B_gb;
    float2 A_wk, B_wk;
    float4 A_fb[16], B_fb[16];

#define LOADG(P, idx) do {                                                   \
        const int nv = (int)s_list[idx];                                     \
        const int ns = __builtin_amdgcn_readfirstlane(nv);                   \
        P##_cu = cull[ns]; P##_cf = coef[ns];                                \
        P##_gb = gab[ns];  P##_wk = wts[ns];                                 \
        const float4* fpv = (const float4*)feats + (opaque_v(nv) << 4);      \
        _Pragma("unroll")                                                    \
        for (int q = 0; q < 16; ++q) P##_fb[q] = fpv[q];                     \
    } while (0)

#define COMPUTE(P) do {                                                      \
        const float dx = P##_cu.x - px, dy = P##_cu.y - py;                  \
        const float sig = 0.5f*(P##_cf.x*dx*dx + P##_cf.z*dy*dy)             \
                        + P##_cf.y*dx*dy;                                    \
        const float a = __expf(-sig) * P##_cu.w;                             \
        const float mfac = 1.f + P##_wk.x*__cosf(P##_gb.x*dx + P##_gb.y*dy)  \
                               + P##_wk.y*__cosf(P##_gb.z*dx + P##_gb.w*dy); \
        const float wgt = a * mfac;                                          \
        _Pragma("unroll")                                                    \
        for (int q = 0; q < 16; ++q) {                                       \
            acc[4*q+0] = fmaf(wgt, P##_fb[q].x, acc[4*q+0]);                 \
            acc[4*q+1] = fmaf(wgt, P##_fb[q].y, acc[4*q+1]);                 \
            acc[4*q+2] = fmaf(wgt, P##_fb[q].z, acc[4*q+2]);                 \
            acc[4*q+3] = fmaf(wgt, P##_fb[q].w, acc[4*q+3]);                 \
        }                                                                    \
    } while (0)

    if (total > 0) {
        LOADG(A, 0);
        int i = 0;
        while (true) {
            bool hasN = (i + 1) < total;
            if (hasN) LOADG(B, i + 1);
            COMPUTE(A);
            ++i;
            if (!hasN) break;
            hasN = (i + 1) < total;
            if (hasN) LOADG(A, i + 1);
            COMPUTE(B);
            ++i;
            if (!hasN) break;
        }
    }
#undef LOADG
#undef COMPUTE

    // store: out[(c, y, x)], lanes contiguous in x (128B rows)
    const int p = ((y0 + ty) << 8) + x0 + tx;
    #pragma unroll
    for (int c = 0; c < NC; ++c)
        out[(c << 16) + p] = fminf(fmaxf(acc[c], 0.f), 1.f);
}

// ---------------------------------------------------------------------------
extern "C" void kernel_launch(void* const* d_in, const int* in_sizes, int n_in,
                              void* d_out, int out_size, void* d_ws, size_t ws_size,
                              hipStream_t stream) {
    const float* xyz  = (const float*)d_in[0];
    const float* chol = (const float*)d_in[1];
    const float* opac = (const float*)d_in[2];
    const float* fdc  = (const float*)d_in[3];
    const float* gfrq = (const float*)d_in[4];
    const float* gwts = (const float*)d_in[5];

    char* ws = (char*)d_ws;
    // ws layout (needs 319488 B): feats 256KB | cull 16KB | coef 16KB | gab 16KB | wts 8KB
    float*  feats = (float*) (ws);
    float4* cull  = (float4*)(ws + 262144);
    float4* coef  = (float4*)(ws + 278528);
    float4* gab   = (float4*)(ws + 294912);
    float2* wtsp  = (float2*)(ws + 311296);

    prep_kernel<<<257, 256, 0, stream>>>(xyz, chol, opac, fdc, gfrq, gwts,
                                         feats, cull, coef, gab, wtsp);
    render_kernel<<<256, 256, 0, stream>>>(feats, cull, coef, gab, wtsp,
                                           (float*)d_out);
}

// Round 3
// 26.354 us; speedup vs baseline: 1.0550x; 1.0550x over previous
//
#include <hip/hip_runtime.h>
#include <hip/hip_bf16.h>

// Problem constants (fixed by the reference)
#define NG   1024
#define IMGW 256
#define IMGH 256
#define NC   64
#define CULL_T 15.0f   // cull when sigma > T; dropped mass <= 1024*2*0.07*e^-15 ~ 4e-5

__device__ __forceinline__ int opaque_v(int x) {
    // Keep dependent loads on the VECTOR path (uniform-address broadcast
    // global_load) instead of scalarizing to s_load.
    int y; asm("v_mov_b32 %0, %1" : "=v"(y) : "v"(x)); return y;
}

// ---------------------------------------------------------------------------
// Kernel 1: per-gaussian parameter precompute + softplus(features) into ws.
// blocks 0..255: feats (65536 softplus). block 256: 1024 gaussians, 4/thread.
// ---------------------------------------------------------------------------
__global__ __launch_bounds__(256) void prep_kernel(
    const float* __restrict__ xyz,  const float* __restrict__ chol,
    const float* __restrict__ opac, const float* __restrict__ fdc,
    const float* __restrict__ gfrq, const float* __restrict__ gwts,
    float*  __restrict__ feats, float4* __restrict__ cull,
    float4* __restrict__ coef,  float4* __restrict__ gab,
    float2* __restrict__ wts)
{
    const int b = blockIdx.x, t = threadIdx.x;
    if (b < 256) {
        const int i = (b << 8) + t;
        const float x = fdc[i];
        feats[i] = x > 0.f ? x + log1pf(expf(-x)) : log1pf(expf(x));
        return;
    }
    for (int j = 0; j < 4; ++j) {
        const int n = (j << 8) + t;
        const float2 xy = ((const float2*)xyz)[n];
        const float xs = 128.f * (tanhf(xy.x) + 1.f);
        const float ys = 128.f * (tanhf(xy.y) + 1.f);

        const float l1 = chol[3*n]     + 0.5f;
        const float l2 = chol[3*n + 1];
        const float l3 = chol[3*n + 2] + 0.5f;
        const float s11 = l1*l1, s12 = l1*l2, s22 = l2*l2 + l3*l3;
        const float dt  = (l1*l3) * (l1*l3);
        const float ca = s22/dt, cb = -(s12/dt), cc = s11/dt;
        const float mid = 0.5f*(s11 + s22);
        const float lam = mid + sqrtf(fmaxf(mid*mid - dt, 1e-8f));
        const float radius = ceilf(3.f * sqrtf(lam));
        const float keep = (radius > 1.0f) ? 1.f : 0.f;   // RADIUS_CLIP = 1.0
        const float oK = opac[n] * keep;
        const float r2 = (oK != 0.f) ? (2.f * CULL_T * lam) : -1.f;

        cull[n] = make_float4(xs, ys, r2, oK);
        coef[n] = make_float4(ca, cb, cc, 0.f);
        const float4 gf = ((const float4*)gfrq)[n];
        gab[n]  = make_float4(expf(gf.x), expf(gf.y), expf(gf.z), expf(gf.w));
        const float2 gw = ((const float2*)gwts)[n];
        wts[n]  = make_float2(1.f/(1.f + expf(-gw.x)), 1.f/(1.f + expf(-gw.y)));
    }
}

// ---------------------------------------------------------------------------
// Kernel 2: one 512-thread block (8 waves) per 32x8 tile. Channel dimension
// split across halves: waves 0-3 -> channels 0..31, waves 4-7 -> 32..63, same
// pixels. 2 waves/SIMD gives TLP to hide list/param/feat load latency.
// Deterministic ballot-compaction (ascending ids) as before.
// ---------------------------------------------------------------------------
__global__ __launch_bounds__(512, 2) void render_kernel(
    const float*  __restrict__ feats, const float4* __restrict__ cull,
    const float4* __restrict__ coef,  const float4* __restrict__ gab,
    const float2* __restrict__ wts,   float* __restrict__ out)
{
    __shared__ unsigned short s_ids[8][128];
    __shared__ int            s_cnt[8];
    __shared__ unsigned short s_list[NG];

    const int tid  = threadIdx.x;
    const int lane = tid & 63, w = tid >> 6;

    const int x0 = (blockIdx.x & 7) << 5;   // 8 tiles across (32 px wide)
    const int y0 = (blockIdx.x >> 3) << 3;  // 32 tiles down  (8 px tall)
    const float xlo = x0 + 0.5f, xhi = x0 + 31.5f;
    const float ylo = y0 + 0.5f, yhi = y0 + 7.5f;

    // phase A: each of 8 waves owns 128 gaussians, 2 ordered rounds of 64
    int cnt = 0;
    for (int r = 0; r < 2; ++r) {
        const int n = (w << 7) + (r << 6) + lane;
        const float4 cu = cull[n];
        const float nx = fminf(fmaxf(cu.x, xlo), xhi);
        const float ny = fminf(fmaxf(cu.y, ylo), yhi);
        const float ddx = cu.x - nx, ddy = cu.y - ny;
        const bool live = (ddx*ddx + ddy*ddy) <= cu.z;   // r2 = -1 kills dead ones
        const unsigned long long m = __ballot(live);
        if (live) {
            const int pos = cnt + __popcll(m & ((1ull << lane) - 1ull));
            s_ids[w][pos] = (unsigned short)n;
        }
        cnt += __popcll(m);
    }
    if (lane == 0) s_cnt[w] = cnt;
    __syncthreads();

    // merge per-wave lists in wave order -> globally ascending ids (determinism)
    int off = 0, tot = 0;
    #pragma unroll
    for (int k = 0; k < 8; ++k) {
        const int ck = s_cnt[k];
        if (k < w) off += ck;
        tot += ck;
    }
    const int myc = s_cnt[w];
    for (int i = lane; i < myc; i += 64) s_list[off + i] = s_ids[w][i];
    __syncthreads();
    const int total = __builtin_amdgcn_readfirstlane(tot);

    // phase B: per-pixel accumulation over 32 channels per half
    const int pid = tid & 255;              // pixel within tile
    const int half = tid >> 8;              // 0: ch 0-31, 1: ch 32-63
    const int c0 = half << 5;
    const int tx = pid & 31, ty = pid >> 5;
    const float px = x0 + tx + 0.5f;
    const float py = y0 + ty + 0.5f;

    float acc[32];
    #pragma unroll
    for (int c = 0; c < 32; ++c) acc[c] = 0.f;

    // named double buffers (static indexing only — rule #20)
    float4 A_cu, A_cf, A_gb, B_cu, B_cf, B_gb;
    float2 A_wk, B_wk;
    float4 A_fb[8], B_fb[8];

#define LOADG(P, idx) do {                                                   \
        const int nv = (int)s_list[idx];                                     \
        const int ns = __builtin_amdgcn_readfirstlane(nv);                   \
        P##_cu = cull[ns]; P##_cf = coef[ns];                                \
        P##_gb = gab[ns];  P##_wk = wts[ns];                                 \
        const float4* fpv = (const float4*)(feats + (opaque_v(nv) << 6) + c0); \
        _Pragma("unroll")                                                    \
        for (int q = 0; q < 8; ++q) P##_fb[q] = fpv[q];                      \
    } while (0)

#define COMPUTE(P) do {                                                      \
        const float dx = P##_cu.x - px, dy = P##_cu.y - py;                  \
        const float sig = 0.5f*(P##_cf.x*dx*dx + P##_cf.z*dy*dy)             \
                        + P##_cf.y*dx*dy;                                    \
        const float a = __expf(-sig) * P##_cu.w;                             \
        const float mfac = 1.f + P##_wk.x*__cosf(P##_gb.x*dx + P##_gb.y*dy)  \
                               + P##_wk.y*__cosf(P##_gb.z*dx + P##_gb.w*dy); \
        const float wgt = a * mfac;                                          \
        _Pragma("unroll")                                                    \
        for (int q = 0; q < 8; ++q) {                                        \
            acc[4*q+0] = fmaf(wgt, P##_fb[q].x, acc[4*q+0]);                 \
            acc[4*q+1] = fmaf(wgt, P##_fb[q].y, acc[4*q+1]);                 \
            acc[4*q+2] = fmaf(wgt, P##_fb[q].z, acc[4*q+2]);                 \
            acc[4*q+3] = fmaf(wgt, P##_fb[q].w, acc[4*q+3]);                 \
        }                                                                    \
    } while (0)

    if (total > 0) {
        LOADG(A, 0);
        int i = 0;
        while (true) {
            bool hasN = (i + 1) < total;
            if (hasN) LOADG(B, i + 1);
            COMPUTE(A);
            ++i;
            if (!hasN) break;
            hasN = (i + 1) < total;
            if (hasN) LOADG(A, i + 1);
            COMPUTE(B);
            ++i;
            if (!hasN) break;
        }
    }
#undef LOADG
#undef COMPUTE

    // store: out[(c, y, x)], lanes contiguous in x (128B rows)
    const int p = ((y0 + ty) << 8) + x0 + tx;
    #pragma unroll
    for (int c = 0; c < 32; ++c)
        out[((c0 + c) << 16) + p] = fminf(fmaxf(acc[c], 0.f), 1.f);
}

// ---------------------------------------------------------------------------
extern "C" void kernel_launch(void* const* d_in, const int* in_sizes, int n_in,
                              void* d_out, int out_size, void* d_ws, size_t ws_size,
                              hipStream_t stream) {
    const float* xyz  = (const float*)d_in[0];
    const float* chol = (const float*)d_in[1];
    const float* opac = (const float*)d_in[2];
    const float* fdc  = (const float*)d_in[3];
    const float* gfrq = (const float*)d_in[4];
    const float* gwts = (const float*)d_in[5];

    char* ws = (char*)d_ws;
    // ws layout (needs 319488 B): feats 256KB | cull 16KB | coef 16KB | gab 16KB | wts 8KB
    float*  feats = (float*) (ws);
    float4* cull  = (float4*)(ws + 262144);
    float4* coef  = (float4*)(ws + 278528);
    float4* gab   = (float4*)(ws + 294912);
    float2* wtsp  = (float2*)(ws + 311296);

    prep_kernel<<<257, 256, 0, stream>>>(xyz, chol, opac, fdc, gfrq, gwts,
                                         feats, cull, coef, gab, wtsp);
    render_kernel<<<256, 512, 0, stream>>>(feats, cull, coef, gab, wtsp,
                                           (float*)d_out);
}

// Round 4
// 19.367 us; speedup vs baseline: 1.4356x; 1.3608x over previous
//
#include <hip/hip_runtime.h>
#include <hip/hip_bf16.h>

// Problem constants (fixed by the reference)
#define NG   1024
#define NC   64
#define CULL_T 15.0f   // cull when sigma > T; dropped mass <= 1024*2*0.07*e^-15 ~ 4e-5
#define MAXL 256       // compacted live-gaussian capacity (worst-case live ~55)
#define MAXC 128       // feats chunk rows (chunked loop for safety; 1 pass typical)

// ---------------------------------------------------------------------------
// Single fused kernel: one 512-thread block per 32x8 tile.
//  Phase 0/A: each thread preps 2 gaussians in registers (tanh/exp/divides),
//             culls vs tile, ballot-compacts ascending ids, and writes the
//             ~25 surviving gaussians' params COMPACTED into LDS.
//  Phase A2:  softplus(features) for live gaussians only -> LDS.
//  Phase B:   per-pixel accumulation; all inner-loop loads are position-
//             indexed LDS broadcasts (no load-dependent address chains).
//  Channel split: waves 0-3 -> ch 0..31, waves 4-7 -> ch 32..63 (2 waves/SIMD).
// ---------------------------------------------------------------------------
__global__ __launch_bounds__(512, 1) void fused_render_kernel(
    const float* __restrict__ xyz,  const float* __restrict__ chol,
    const float* __restrict__ opac, const float* __restrict__ fdc,
    const float* __restrict__ gfrq, const float* __restrict__ gwts,
    float* __restrict__ out)
{
    __shared__ float4 s_p0[MAXL];              // (xs, ys, ca, cb)
    __shared__ float4 s_p1[MAXL];              // (cc, oK, wk0, wk1)
    __shared__ float4 s_p2[MAXL];              // (f00, f01, f10, f11)
    __shared__ unsigned short s_list[MAXL];    // gaussian id per list pos
    __shared__ float  s_feat[MAXC][NC];        // 32KB
    __shared__ int    s_scnt[16];              // per-(round,wave) live counts

    const int tid  = threadIdx.x;
    const int lane = tid & 63, w = tid >> 6;

    const int x0 = (blockIdx.x & 7) << 5;   // 8 tiles across (32 px wide)
    const int y0 = (blockIdx.x >> 3) << 3;  // 32 tiles down  (8 px tall)
    const float xlo = x0 + 0.5f, xhi = x0 + 31.5f;
    const float ylo = y0 + 0.5f, yhi = y0 + 7.5f;

    // ---- Phase 0/A: prep + cull, params held in registers --------------
    float4 P0[2], P1[2], P2[2];
    bool   liveR[2];
    int    posR[2];
    #pragma unroll
    for (int r = 0; r < 2; ++r) {
        const int n = (r << 9) + tid;        // r-major => ascending ids
        const float2 xy = ((const float2*)xyz)[n];
        const float xs = 128.f * (tanhf(xy.x) + 1.f);
        const float ys = 128.f * (tanhf(xy.y) + 1.f);

        const float l1 = chol[3*n]     + 0.5f;
        const float l2 = chol[3*n + 1];
        const float l3 = chol[3*n + 2] + 0.5f;
        const float s11 = l1*l1, s12 = l1*l2, s22 = l2*l2 + l3*l3;
        const float dt  = (l1*l3) * (l1*l3);
        const float ca = s22/dt, cb = -(s12/dt), cc = s11/dt;
        const float mid = 0.5f*(s11 + s22);
        const float lam = mid + sqrtf(fmaxf(mid*mid - dt, 1e-8f));
        const float radius = ceilf(3.f * sqrtf(lam));
        const float keep = (radius > 1.0f) ? 1.f : 0.f;   // RADIUS_CLIP = 1.0
        const float oK = opac[n] * keep;
        const float r2 = (oK != 0.f) ? (2.f * CULL_T * lam) : -1.f;

        // point-in-rounded-rect cull against this tile
        const float nx = fminf(fmaxf(xs, xlo), xhi);
        const float ny = fminf(fmaxf(ys, ylo), yhi);
        const float ddx = xs - nx, ddy = ys - ny;
        const bool live = (ddx*ddx + ddy*ddy) <= r2;

        const unsigned long long m = __ballot(live);
        liveR[r] = live;
        posR[r]  = __popcll(m & ((1ull << lane) - 1ull));
        if (lane == 0) s_scnt[(r << 3) + w] = __popcll(m);

        const float4 gf = ((const float4*)gfrq)[n];
        const float2 gw = ((const float2*)gwts)[n];
        P0[r] = make_float4(xs, ys, ca, cb);
        P1[r] = make_float4(cc, oK, 1.f/(1.f + __expf(-gw.x)),
                                    1.f/(1.f + __expf(-gw.y)));
        P2[r] = make_float4(__expf(gf.x), __expf(gf.y),
                            __expf(gf.z), __expf(gf.w));
    }
    __syncthreads();

    // exclusive prefix over the 16 (round-major) segments -> ascending ids
    int off0 = 0, off1 = 0, tot = 0;
    #pragma unroll
    for (int s = 0; s < 16; ++s) {
        const int c = s_scnt[s];
        if (s < w)     off0 += c;   // r=0 segment index = w
        if (s < 8 + w) off1 += c;   // r=1 segment index = 8+w
        tot += c;
    }
    if (liveR[0]) {
        const int p = off0 + posR[0];
        if (p < MAXL) { s_list[p] = (unsigned short)tid;
                        s_p0[p] = P0[0]; s_p1[p] = P1[0]; s_p2[p] = P2[0]; }
    }
    if (liveR[1]) {
        const int p = off1 + posR[1];
        if (p < MAXL) { s_list[p] = (unsigned short)(512 + tid);
                        s_p0[p] = P0[1]; s_p1[p] = P1[1]; s_p2[p] = P2[1]; }
    }
    __syncthreads();
    const int total = min(__builtin_amdgcn_readfirstlane(tot), MAXL);

    // ---- Phase B: per-pixel accumulation --------------------------------
    const int pid = tid & 255;               // pixel within tile
    const int c0  = (tid >> 8) << 5;         // channel half: 0 or 32
    const int tx  = pid & 31, ty = pid >> 5;
    const float px = x0 + tx + 0.5f;
    const float py = y0 + ty + 0.5f;

    float acc[32];
    #pragma unroll
    for (int c = 0; c < 32; ++c) acc[c] = 0.f;

    for (int base = 0; base < total; base += MAXC) {
        const int clen = min(total - base, MAXC);

        // softplus(features) for this chunk's live gaussians -> LDS
        for (int v = tid; v < (clen << 6); v += 512) {
            const int j = v >> 6, c = v & 63;
            const int n = (int)s_list[base + j];
            const float x = fdc[(n << 6) + c];
            s_feat[j][c] = x > 0.f ? x + log1pf(__expf(-x))
                                   : log1pf(__expf(x));
        }
        __syncthreads();

        for (int i = 0; i < clen; ++i) {
            const float4 p0 = s_p0[base + i];   // loop-static broadcast reads
            const float4 p1 = s_p1[base + i];
            const float4 p2 = s_p2[base + i];

            const float dx = p0.x - px, dy = p0.y - py;
            const float sig = 0.5f*(p0.z*dx*dx + p1.x*dy*dy) + p0.w*dx*dy;
            const float a = __expf(-sig) * p1.y;
            const float mfac = 1.f + p1.z*__cosf(p2.x*dx + p2.y*dy)
                                   + p1.w*__cosf(p2.z*dx + p2.w*dy);
            const float wgt = a * mfac;

            const float4* fl = (const float4*)(&s_feat[i][c0]);
            #pragma unroll
            for (int q = 0; q < 8; ++q) {
                const float4 f = fl[q];
                acc[4*q+0] = fmaf(wgt, f.x, acc[4*q+0]);
                acc[4*q+1] = fmaf(wgt, f.y, acc[4*q+1]);
                acc[4*q+2] = fmaf(wgt, f.z, acc[4*q+2]);
                acc[4*q+3] = fmaf(wgt, f.w, acc[4*q+3]);
            }
        }
        __syncthreads();
    }

    // store: out[(c, y, x)], each wave's store is 256B contiguous
    const int p = ((y0 + ty) << 8) + x0 + tx;
    #pragma unroll
    for (int c = 0; c < 32; ++c)
        out[((c0 + c) << 16) + p] = fminf(fmaxf(acc[c], 0.f), 1.f);
}

// ---------------------------------------------------------------------------
extern "C" void kernel_launch(void* const* d_in, const int* in_sizes, int n_in,
                              void* d_out, int out_size, void* d_ws, size_t ws_size,
                              hipStream_t stream) {
    const float* xyz  = (const float*)d_in[0];
    const float* chol = (const float*)d_in[1];
    const float* opac = (const float*)d_in[2];
    const float* fdc  = (const float*)d_in[3];
    const float* gfrq = (const float*)d_in[4];
    const float* gwts = (const float*)d_in[5];

    fused_render_kernel<<<256, 512, 0, stream>>>(xyz, chol, opac, fdc,
                                                 gfrq, gwts, (float*)d_out);
}